// Round 1
// baseline (1559.516 us; speedup 1.0000x reference)
//
#include <hip/hip_runtime.h>
#include <math.h>

#define N_NODES 1000000
#define N_EDGES 32000000

__global__ __launch_bounds__(256) void zero_kernel(float* __restrict__ agg, int n) {
    int i = blockIdx.x * blockDim.x + threadIdx.x;
    if (i < n) agg[i] = 0.0f;
}

__global__ __launch_bounds__(256) void edge_kernel(
    const float* __restrict__ node_output,
    const float* __restrict__ edge_weight,
    const int* __restrict__ edge_src,
    const int* __restrict__ edge_dst,
    float* __restrict__ agg,
    int n_edges)
{
    int tid = blockIdx.x * blockDim.x + threadIdx.x;
    int stride = gridDim.x * blockDim.x;
    int n4 = n_edges >> 2;
    for (int i = tid; i < n4; i += stride) {
        int4   src = ((const int4*)edge_src)[i];
        int4   dst = ((const int4*)edge_dst)[i];
        float4 w   = ((const float4*)edge_weight)[i];
        atomicAdd(&agg[dst.x], node_output[src.x] * w.x);
        atomicAdd(&agg[dst.y], node_output[src.y] * w.y);
        atomicAdd(&agg[dst.z], node_output[src.z] * w.z);
        atomicAdd(&agg[dst.w], node_output[src.w] * w.w);
    }
    // tail for n_edges not divisible by 4 (not the case here, but safe)
    for (int i = (n4 << 2) + tid; i < n_edges; i += stride) {
        atomicAdd(&agg[edge_dst[i]], node_output[edge_src[i]] * edge_weight[i]);
    }
}

__global__ __launch_bounds__(256) void node_kernel(
    const float* __restrict__ agg,
    const float* __restrict__ node_params,
    float* __restrict__ out,
    int n)
{
    int i = blockIdx.x * blockDim.x + threadIdx.x;
    if (i >= n) return;
    const float* p = node_params + (size_t)i * 7;
    float x  = agg[i] + p[0];
    float a0 = p[1];
    float a1 = p[2];
    float a2 = p[3];
    float a3 = p[4];
    float a4 = p[5];
    out[i] = a0 * tanhf(x) * sinf(a1 * x + a2) + a3 * x + a4;
}

extern "C" void kernel_launch(void* const* d_in, const int* in_sizes, int n_in,
                              void* d_out, int out_size, void* d_ws, size_t ws_size,
                              hipStream_t stream) {
    const float* node_output = (const float*)d_in[0];
    const float* edge_weight = (const float*)d_in[1];
    const float* node_params = (const float*)d_in[2];
    const int*   edge_src    = (const int*)d_in[3];
    const int*   edge_dst    = (const int*)d_in[4];
    float* out = (float*)d_out;
    float* agg = (float*)d_ws;   // N_NODES floats of scratch

    int n_nodes = in_sizes[0];
    int n_edges = in_sizes[1];

    int zb = (n_nodes + 255) / 256;
    zero_kernel<<<zb, 256, 0, stream>>>(agg, n_nodes);

    int eb = 4096;   // grid-stride over 8M vec4 iterations
    edge_kernel<<<eb, 256, 0, stream>>>(node_output, edge_weight, edge_src, edge_dst,
                                        agg, n_edges);

    node_kernel<<<zb, 256, 0, stream>>>(agg, node_params, out, n_nodes);
}

// Round 2
// 756.321 us; speedup vs baseline: 2.0620x; 2.0620x over previous
//
#include <hip/hip_runtime.h>
#include <math.h>

// ---------------- multisplit parameters ----------------
#define NBINS      128          // bin = dst >> 13 ; covers up to 2^20 nodes
#define BIN_SHIFT  13
#define BIN_SIZE   8192         // nodes per bin (32 KB fp32 in LDS)
#define NBLK2      1024         // blocks in hist/scatter
#define BLK2       256          // threads in hist/scatter
#define SSUB       8            // sub-blocks per bin in accumulate

// ============================================================
// FAST PATH: deterministic multisplit + LDS accumulation
// ============================================================

// K1: per-(block,bin) histogram of dst
__global__ __launch_bounds__(BLK2) void hist_kernel(
    const int* __restrict__ edge_dst, int n_edges,
    int* __restrict__ counts_g,      // [NBINS][NBLK2]
    int* __restrict__ bin_tot)       // [NBINS], pre-zeroed
{
    __shared__ int cnt[NBINS];
    int tid = threadIdx.x;
    for (int i = tid; i < NBINS; i += blockDim.x) cnt[i] = 0;
    __syncthreads();

    int nvec4 = n_edges >> 2;
    int stride = gridDim.x * blockDim.x;
    for (int v = blockIdx.x * blockDim.x + tid; v < nvec4; v += stride) {
        int4 d = ((const int4*)edge_dst)[v];
        atomicAdd(&cnt[d.x >> BIN_SHIFT], 1);
        atomicAdd(&cnt[d.y >> BIN_SHIFT], 1);
        atomicAdd(&cnt[d.z >> BIN_SHIFT], 1);
        atomicAdd(&cnt[d.w >> BIN_SHIFT], 1);
    }
    if (blockIdx.x == 0 && tid == 0) {          // scalar tail -> block 0
        for (int i = nvec4 << 2; i < n_edges; ++i)
            atomicAdd(&cnt[edge_dst[i] >> BIN_SHIFT], 1);
    }
    __syncthreads();
    for (int i = tid; i < NBINS; i += blockDim.x) {
        counts_g[i * NBLK2 + blockIdx.x] = cnt[i];
        atomicAdd(&bin_tot[i], cnt[i]);          // int atomics: deterministic
    }
}

// K2: exclusive scan of bin totals -> bin_base[NBINS+1]
__global__ __launch_bounds__(NBINS) void scan_bins_kernel(
    const int* __restrict__ bin_tot, int* __restrict__ bin_base)
{
    __shared__ int s[NBINS];
    int tid = threadIdx.x;
    int x = bin_tot[tid];
    s[tid] = x;
    __syncthreads();
    for (int off = 1; off < NBINS; off <<= 1) {
        int t = (tid >= off) ? s[tid - off] : 0;
        __syncthreads();
        s[tid] += t;
        __syncthreads();
    }
    bin_base[tid + 1] = s[tid];                  // inclusive -> base[i+1]
    if (tid == 0) bin_base[0] = 0;
}

// K3: per-bin exclusive scan over the NBLK2 block counts (in place -> offsets)
__global__ __launch_bounds__(NBLK2) void scan_blocks_kernel(
    int* __restrict__ counts_g, const int* __restrict__ bin_base)
{
    __shared__ int s[NBLK2];
    int b = blockIdx.x, tid = threadIdx.x;
    int x = counts_g[b * NBLK2 + tid];
    s[tid] = x;
    __syncthreads();
    for (int off = 1; off < NBLK2; off <<= 1) {
        int t = (tid >= off) ? s[tid - off] : 0;
        __syncthreads();
        s[tid] += t;
        __syncthreads();
    }
    counts_g[b * NBLK2 + tid] = bin_base[b] + s[tid] - x;   // exclusive + base
}

// K4: scatter (dst_local, msg) pairs into bin-major buffer at exact offsets
__global__ __launch_bounds__(BLK2) void scatter_kernel(
    const float* __restrict__ node_output,
    const float* __restrict__ edge_weight,
    const int* __restrict__ edge_src,
    const int* __restrict__ edge_dst,
    const int* __restrict__ offsets_g,   // [NBINS][NBLK2]
    uint2* __restrict__ pairs,
    int n_edges)
{
    __shared__ int cur[NBINS];
    int tid = threadIdx.x, blk = blockIdx.x;
    for (int i = tid; i < NBINS; i += blockDim.x)
        cur[i] = offsets_g[i * NBLK2 + blk];
    __syncthreads();

    int nvec4 = n_edges >> 2;
    int stride = gridDim.x * blockDim.x;
    for (int v = blk * blockDim.x + tid; v < nvec4; v += stride) {
        int4   s4 = ((const int4*)edge_src)[v];
        int4   d4 = ((const int4*)edge_dst)[v];
        float4 w4 = ((const float4*)edge_weight)[v];
        float m0 = node_output[s4.x] * w4.x;
        float m1 = node_output[s4.y] * w4.y;
        float m2 = node_output[s4.z] * w4.z;
        float m3 = node_output[s4.w] * w4.w;
        int p0 = atomicAdd(&cur[d4.x >> BIN_SHIFT], 1);
        pairs[p0] = make_uint2((unsigned)(d4.x & (BIN_SIZE - 1)), __float_as_uint(m0));
        int p1 = atomicAdd(&cur[d4.y >> BIN_SHIFT], 1);
        pairs[p1] = make_uint2((unsigned)(d4.y & (BIN_SIZE - 1)), __float_as_uint(m1));
        int p2 = atomicAdd(&cur[d4.z >> BIN_SHIFT], 1);
        pairs[p2] = make_uint2((unsigned)(d4.z & (BIN_SIZE - 1)), __float_as_uint(m2));
        int p3 = atomicAdd(&cur[d4.w >> BIN_SHIFT], 1);
        pairs[p3] = make_uint2((unsigned)(d4.w & (BIN_SIZE - 1)), __float_as_uint(m3));
    }
    if (blk == 0 && tid == 0) {                   // scalar tail -> block 0
        for (int i = nvec4 << 2; i < n_edges; ++i) {
            int d = edge_dst[i];
            float m = node_output[edge_src[i]] * edge_weight[i];
            int p = atomicAdd(&cur[d >> BIN_SHIFT], 1);
            pairs[p] = make_uint2((unsigned)(d & (BIN_SIZE - 1)), __float_as_uint(m));
        }
    }
}

// K5: per-(bin, sub-block) LDS accumulation -> partials
__global__ __launch_bounds__(512) void accum_kernel(
    const uint2* __restrict__ pairs,
    const int* __restrict__ bin_base,
    float* __restrict__ partials)        // [NBINS*SSUB][BIN_SIZE]
{
    __shared__ float acc[BIN_SIZE];
    int b = blockIdx.x / SSUB, s = blockIdx.x % SSUB, tid = threadIdx.x;
    for (int i = tid; i < BIN_SIZE; i += blockDim.x) acc[i] = 0.0f;
    __syncthreads();

    int lo = bin_base[b], hi = bin_base[b + 1];
    int tot = hi - lo;
    int chunk = (tot + SSUB - 1) / SSUB;
    int start = lo + s * chunk;
    int end = min(start + chunk, hi);
    for (int i = start + tid; i < end; i += blockDim.x) {
        uint2 pr = pairs[i];
        atomicAdd(&acc[pr.x], __uint_as_float(pr.y));   // LDS fp32 atomic
    }
    __syncthreads();

    float4* dst = (float4*)(partials + (size_t)blockIdx.x * BIN_SIZE);
    const float4* src = (const float4*)acc;
    for (int i = tid; i < BIN_SIZE / 4; i += blockDim.x) dst[i] = src[i];
}

// K6: fused partial-reduce + elementwise math
__global__ __launch_bounds__(512) void node_fused_kernel(
    const float* __restrict__ partials,
    const float* __restrict__ node_params,
    float* __restrict__ out, int n)
{
    int i = blockIdx.x * blockDim.x + threadIdx.x;
    if (i >= n) return;
    int b = i >> BIN_SHIFT, j = i & (BIN_SIZE - 1);
    const float* pb = partials + ((size_t)b * SSUB) * BIN_SIZE + j;
    float x = 0.0f;
    #pragma unroll
    for (int s = 0; s < SSUB; ++s) x += pb[(size_t)s * BIN_SIZE];
    const float* p = node_params + (size_t)i * 7;
    x += p[0];
    out[i] = p[1] * tanhf(x) * sinf(p[2] * x + p[3]) + p[4] * x + p[5];
}

// ============================================================
// FALLBACK PATH (R1 atomic version) if ws too small
// ============================================================
__global__ __launch_bounds__(256) void zero_kernel(float* __restrict__ agg, int n) {
    int i = blockIdx.x * blockDim.x + threadIdx.x;
    if (i < n) agg[i] = 0.0f;
}
__global__ __launch_bounds__(256) void edge_kernel(
    const float* __restrict__ node_output, const float* __restrict__ edge_weight,
    const int* __restrict__ edge_src, const int* __restrict__ edge_dst,
    float* __restrict__ agg, int n_edges)
{
    int tid = blockIdx.x * blockDim.x + threadIdx.x;
    int stride = gridDim.x * blockDim.x;
    int n4 = n_edges >> 2;
    for (int i = tid; i < n4; i += stride) {
        int4   src = ((const int4*)edge_src)[i];
        int4   dst = ((const int4*)edge_dst)[i];
        float4 w   = ((const float4*)edge_weight)[i];
        atomicAdd(&agg[dst.x], node_output[src.x] * w.x);
        atomicAdd(&agg[dst.y], node_output[src.y] * w.y);
        atomicAdd(&agg[dst.z], node_output[src.z] * w.z);
        atomicAdd(&agg[dst.w], node_output[src.w] * w.w);
    }
    for (int i = (n4 << 2) + tid; i < n_edges; i += stride)
        atomicAdd(&agg[edge_dst[i]], node_output[edge_src[i]] * edge_weight[i]);
}
__global__ __launch_bounds__(256) void node_kernel(
    const float* __restrict__ agg, const float* __restrict__ node_params,
    float* __restrict__ out, int n)
{
    int i = blockIdx.x * blockDim.x + threadIdx.x;
    if (i >= n) return;
    const float* p = node_params + (size_t)i * 7;
    float x = agg[i] + p[0];
    out[i] = p[1] * tanhf(x) * sinf(p[2] * x + p[3]) + p[4] * x + p[5];
}

// ============================================================
extern "C" void kernel_launch(void* const* d_in, const int* in_sizes, int n_in,
                              void* d_out, int out_size, void* d_ws, size_t ws_size,
                              hipStream_t stream) {
    const float* node_output = (const float*)d_in[0];
    const float* edge_weight = (const float*)d_in[1];
    const float* node_params = (const float*)d_in[2];
    const int*   edge_src    = (const int*)d_in[3];
    const int*   edge_dst    = (const int*)d_in[4];
    float* out = (float*)d_out;

    int n_nodes = in_sizes[0];
    int n_edges = in_sizes[1];

    // workspace layout
    size_t pairs_bytes    = (size_t)n_edges * sizeof(uint2);                  // 256 MB
    size_t partials_elems = (size_t)NBINS * SSUB * BIN_SIZE;                  // 8M floats
    size_t partials_bytes = partials_elems * sizeof(float);                   // 32 MB
    size_t counts_elems   = (size_t)NBINS * NBLK2;
    size_t counts_bytes   = counts_elems * sizeof(int);                       // 512 KB
    size_t small_bytes    = (size_t)(NBINS + NBINS + 1 + 16) * sizeof(int);
    size_t need = pairs_bytes + partials_bytes + counts_bytes + small_bytes;

    bool fast = (ws_size >= need) && (n_nodes <= NBINS * BIN_SIZE) && (n_edges >= 4);

    if (fast) {
        uint2* pairs    = (uint2*)d_ws;
        float* partials = (float*)((char*)d_ws + pairs_bytes);
        int*   counts   = (int*)((char*)d_ws + pairs_bytes + partials_bytes);
        int*   bin_tot  = counts + counts_elems;
        int*   bin_base = bin_tot + NBINS;

        hipMemsetAsync(bin_tot, 0, NBINS * sizeof(int), stream);
        hist_kernel<<<NBLK2, BLK2, 0, stream>>>(edge_dst, n_edges, counts, bin_tot);
        scan_bins_kernel<<<1, NBINS, 0, stream>>>(bin_tot, bin_base);
        scan_blocks_kernel<<<NBINS, NBLK2, 0, stream>>>(counts, bin_base);
        scatter_kernel<<<NBLK2, BLK2, 0, stream>>>(node_output, edge_weight,
                                                   edge_src, edge_dst,
                                                   counts, pairs, n_edges);
        accum_kernel<<<NBINS * SSUB, 512, 0, stream>>>(pairs, bin_base, partials);
        int nb = (n_nodes + 511) / 512;
        node_fused_kernel<<<nb, 512, 0, stream>>>(partials, node_params, out, n_nodes);
    } else {
        float* agg = (float*)d_ws;
        int zb = (n_nodes + 255) / 256;
        zero_kernel<<<zb, 256, 0, stream>>>(agg, n_nodes);
        edge_kernel<<<4096, 256, 0, stream>>>(node_output, edge_weight,
                                              edge_src, edge_dst, agg, n_edges);
        node_kernel<<<zb, 256, 0, stream>>>(agg, node_params, out, n_nodes);
    }
}

// Round 3
// 600.394 us; speedup vs baseline: 2.5975x; 1.2597x over previous
//
#include <hip/hip_runtime.h>
#include <math.h>

// ---------------- multisplit parameters ----------------
#define NBINS      128          // bin = dst >> 13 ; covers up to 2^20 nodes
#define BIN_SHIFT  13
#define BIN_SIZE   8192         // nodes per bin (32 KB fp32 in LDS)
#define NBLK2      1024         // blocks in hist/scatter
#define BLK2       256          // threads in hist/scatter
#define TILE       2048         // edges per tile (8 per thread)
#define SSUB       8            // sub-blocks per bin in accumulate

// ============================================================
// FAST PATH: deterministic multisplit + tile-local sort + LDS accumulation
// ============================================================

// K1: per-(block,bin) histogram of dst — tile mapping IDENTICAL to scatter
__global__ __launch_bounds__(BLK2) void hist_kernel(
    const int* __restrict__ edge_dst, int n_edges,
    int* __restrict__ counts_g,      // [NBINS][NBLK2]
    int* __restrict__ bin_tot)       // [NBINS], pre-zeroed
{
    __shared__ int cnt[NBINS];
    int tid = threadIdx.x;
    for (int i = tid; i < NBINS; i += BLK2) cnt[i] = 0;
    __syncthreads();

    int ntiles = (n_edges + TILE - 1) / TILE;
    for (int t = blockIdx.x; t < ntiles; t += gridDim.x) {
        int base = t * TILE;
        #pragma unroll
        for (int g = 0; g < 2; ++g) {
            int e = base + g * (TILE / 2) + tid * 4;
            if (e + 3 < n_edges) {
                int4 d = *(const int4*)(edge_dst + e);
                atomicAdd(&cnt[d.x >> BIN_SHIFT], 1);
                atomicAdd(&cnt[d.y >> BIN_SHIFT], 1);
                atomicAdd(&cnt[d.z >> BIN_SHIFT], 1);
                atomicAdd(&cnt[d.w >> BIN_SHIFT], 1);
            } else {
                for (int k = e; k < n_edges && k < e + 4; ++k)
                    atomicAdd(&cnt[edge_dst[k] >> BIN_SHIFT], 1);
            }
        }
    }
    __syncthreads();
    for (int i = tid; i < NBINS; i += BLK2) {
        counts_g[i * NBLK2 + blockIdx.x] = cnt[i];
        atomicAdd(&bin_tot[i], cnt[i]);          // int atomics: deterministic
    }
}

// K2: exclusive scan of bin totals -> bin_base[NBINS+1]
__global__ __launch_bounds__(NBINS) void scan_bins_kernel(
    const int* __restrict__ bin_tot, int* __restrict__ bin_base)
{
    __shared__ int s[NBINS];
    int tid = threadIdx.x;
    int x = bin_tot[tid];
    s[tid] = x;
    __syncthreads();
    for (int off = 1; off < NBINS; off <<= 1) {
        int t = (tid >= off) ? s[tid - off] : 0;
        __syncthreads();
        s[tid] += t;
        __syncthreads();
    }
    bin_base[tid + 1] = s[tid];                  // inclusive -> base[i+1]
    if (tid == 0) bin_base[0] = 0;
}

// K3: per-bin exclusive scan over the NBLK2 block counts (in place -> offsets)
__global__ __launch_bounds__(NBLK2) void scan_blocks_kernel(
    int* __restrict__ counts_g, const int* __restrict__ bin_base)
{
    __shared__ int s[NBLK2];
    int b = blockIdx.x, tid = threadIdx.x;
    int x = counts_g[b * NBLK2 + tid];
    s[tid] = x;
    __syncthreads();
    for (int off = 1; off < NBLK2; off <<= 1) {
        int t = (tid >= off) ? s[tid - off] : 0;
        __syncthreads();
        s[tid] += t;
        __syncthreads();
    }
    counts_g[b * NBLK2 + tid] = bin_base[b] + s[tid] - x;   // exclusive + base
}

// K4: tile-local sort by bin in LDS, then coalesced bulk write of pairs
__global__ __launch_bounds__(BLK2) void scatter_kernel(
    const float* __restrict__ node_output,
    const float* __restrict__ edge_weight,
    const int* __restrict__ edge_src,
    const int* __restrict__ edge_dst,
    const int* __restrict__ offsets_g,   // [NBINS][NBLK2]
    uint2* __restrict__ pairs,
    int n_edges)
{
    __shared__ int   gcur[NBINS];        // this block's running cursor per bin
    __shared__ int   hist[NBINS];
    __shared__ int   binoff[NBINS + 1];  // per-tile exclusive scan
    __shared__ int   cursor[NBINS];      // per-tile placement cursor
    __shared__ uint2 pl[TILE];           // bin-sorted staging

    int tid = threadIdx.x, blk = blockIdx.x;
    for (int i = tid; i < NBINS; i += BLK2) {
        gcur[i] = offsets_g[i * NBLK2 + blk];
        hist[i] = 0;
    }
    __syncthreads();

    int ntiles = (n_edges + TILE - 1) / TILE;
    for (int t = blk; t < ntiles; t += gridDim.x) {
        int base = t * TILE;
        int   d[8];
        float m[8];

        // load + msg + per-tile histogram
        #pragma unroll
        for (int g = 0; g < 2; ++g) {
            int e = base + g * (TILE / 2) + tid * 4;
            if (e + 3 < n_edges) {
                int4   s4 = *(const int4*)(edge_src + e);
                int4   d4 = *(const int4*)(edge_dst + e);
                float4 w4 = *(const float4*)(edge_weight + e);
                d[4*g+0] = d4.x; m[4*g+0] = node_output[s4.x] * w4.x;
                d[4*g+1] = d4.y; m[4*g+1] = node_output[s4.y] * w4.y;
                d[4*g+2] = d4.z; m[4*g+2] = node_output[s4.z] * w4.z;
                d[4*g+3] = d4.w; m[4*g+3] = node_output[s4.w] * w4.w;
            } else {
                #pragma unroll
                for (int j = 0; j < 4; ++j) {
                    int k = e + j;
                    if (k < n_edges) {
                        d[4*g+j] = edge_dst[k];
                        m[4*g+j] = node_output[edge_src[k]] * edge_weight[k];
                    } else {
                        d[4*g+j] = -1;
                    }
                }
            }
        }
        #pragma unroll
        for (int j = 0; j < 8; ++j)
            if (d[j] >= 0) atomicAdd(&hist[d[j] >> BIN_SHIFT], 1);
        __syncthreads();

        // scan hist[128] by wave 0 (2 elements per lane, shfl-scan)
        if (tid < 64) {
            int a = hist[2*tid], b = hist[2*tid+1];
            int s = a + b;
            #pragma unroll
            for (int off = 1; off < 64; off <<= 1) {
                int v = __shfl_up(s, off);
                if (tid >= off) s += v;
            }
            int excl = s - (a + b);
            binoff[2*tid]   = excl;     cursor[2*tid]   = excl;
            binoff[2*tid+1] = excl + a; cursor[2*tid+1] = excl + a;
            if (tid == 63) binoff[NBINS] = s;
        }
        __syncthreads();
        int tcount = binoff[NBINS];

        // place into bin-sorted LDS staging (store full dst so bin is recoverable)
        #pragma unroll
        for (int j = 0; j < 8; ++j) {
            if (d[j] >= 0) {
                int b = d[j] >> BIN_SHIFT;
                int pos = atomicAdd(&cursor[b], 1);
                pl[pos] = make_uint2((unsigned)d[j], __float_as_uint(m[j]));
            }
        }
        __syncthreads();

        // coalesced write-out: consecutive k within a bin segment -> consecutive
        // global addresses (segments avg TILE/NBINS = 16 pairs = 128 B)
        for (int k = tid; k < tcount; k += BLK2) {
            uint2 pr = pl[k];
            int b = pr.x >> BIN_SHIFT;
            int gp = gcur[b] + (k - binoff[b]);
            pairs[gp] = make_uint2(pr.x & (BIN_SIZE - 1), pr.y);
        }
        __syncthreads();

        // advance cursors, reset hist for next tile
        if (tid < NBINS) {
            gcur[tid] += binoff[tid + 1] - binoff[tid];
            hist[tid] = 0;
        }
        __syncthreads();
    }
}

// K5: per-(bin, sub-block) LDS accumulation -> partials
__global__ __launch_bounds__(512) void accum_kernel(
    const uint2* __restrict__ pairs,
    const int* __restrict__ bin_base,
    float* __restrict__ partials)        // [NBINS*SSUB][BIN_SIZE]
{
    __shared__ float acc[BIN_SIZE];
    int b = blockIdx.x / SSUB, s = blockIdx.x % SSUB, tid = threadIdx.x;
    for (int i = tid; i < BIN_SIZE; i += blockDim.x) acc[i] = 0.0f;
    __syncthreads();

    int lo = bin_base[b], hi = bin_base[b + 1];
    int tot = hi - lo;
    int chunk = (tot + SSUB - 1) / SSUB;
    int start = lo + s * chunk;
    int end = min(start + chunk, hi);
    for (int i = start + tid; i < end; i += blockDim.x) {
        uint2 pr = pairs[i];
        atomicAdd(&acc[pr.x], __uint_as_float(pr.y));   // LDS fp32 atomic
    }
    __syncthreads();

    float4* dst = (float4*)(partials + (size_t)blockIdx.x * BIN_SIZE);
    const float4* src = (const float4*)acc;
    for (int i = tid; i < BIN_SIZE / 4; i += blockDim.x) dst[i] = src[i];
}

// K6: fused partial-reduce + elementwise math
__global__ __launch_bounds__(512) void node_fused_kernel(
    const float* __restrict__ partials,
    const float* __restrict__ node_params,
    float* __restrict__ out, int n)
{
    int i = blockIdx.x * blockDim.x + threadIdx.x;
    if (i >= n) return;
    int b = i >> BIN_SHIFT, j = i & (BIN_SIZE - 1);
    const float* pb = partials + ((size_t)b * SSUB) * BIN_SIZE + j;
    float x = 0.0f;
    #pragma unroll
    for (int s = 0; s < SSUB; ++s) x += pb[(size_t)s * BIN_SIZE];
    const float* p = node_params + (size_t)i * 7;
    x += p[0];
    out[i] = p[1] * tanhf(x) * sinf(p[2] * x + p[3]) + p[4] * x + p[5];
}

// ============================================================
// FALLBACK PATH (atomic version) if ws too small
// ============================================================
__global__ __launch_bounds__(256) void zero_kernel(float* __restrict__ agg, int n) {
    int i = blockIdx.x * blockDim.x + threadIdx.x;
    if (i < n) agg[i] = 0.0f;
}
__global__ __launch_bounds__(256) void edge_kernel(
    const float* __restrict__ node_output, const float* __restrict__ edge_weight,
    const int* __restrict__ edge_src, const int* __restrict__ edge_dst,
    float* __restrict__ agg, int n_edges)
{
    int tid = blockIdx.x * blockDim.x + threadIdx.x;
    int stride = gridDim.x * blockDim.x;
    int n4 = n_edges >> 2;
    for (int i = tid; i < n4; i += stride) {
        int4   src = ((const int4*)edge_src)[i];
        int4   dst = ((const int4*)edge_dst)[i];
        float4 w   = ((const float4*)edge_weight)[i];
        atomicAdd(&agg[dst.x], node_output[src.x] * w.x);
        atomicAdd(&agg[dst.y], node_output[src.y] * w.y);
        atomicAdd(&agg[dst.z], node_output[src.z] * w.z);
        atomicAdd(&agg[dst.w], node_output[src.w] * w.w);
    }
    for (int i = (n4 << 2) + tid; i < n_edges; i += stride)
        atomicAdd(&agg[edge_dst[i]], node_output[edge_src[i]] * edge_weight[i]);
}
__global__ __launch_bounds__(256) void node_kernel(
    const float* __restrict__ agg, const float* __restrict__ node_params,
    float* __restrict__ out, int n)
{
    int i = blockIdx.x * blockDim.x + threadIdx.x;
    if (i >= n) return;
    const float* p = node_params + (size_t)i * 7;
    float x = agg[i] + p[0];
    out[i] = p[1] * tanhf(x) * sinf(p[2] * x + p[3]) + p[4] * x + p[5];
}

// ============================================================
extern "C" void kernel_launch(void* const* d_in, const int* in_sizes, int n_in,
                              void* d_out, int out_size, void* d_ws, size_t ws_size,
                              hipStream_t stream) {
    const float* node_output = (const float*)d_in[0];
    const float* edge_weight = (const float*)d_in[1];
    const float* node_params = (const float*)d_in[2];
    const int*   edge_src    = (const int*)d_in[3];
    const int*   edge_dst    = (const int*)d_in[4];
    float* out = (float*)d_out;

    int n_nodes = in_sizes[0];
    int n_edges = in_sizes[1];

    // workspace layout
    size_t pairs_bytes    = (size_t)n_edges * sizeof(uint2);                  // 256 MB
    size_t partials_elems = (size_t)NBINS * SSUB * BIN_SIZE;                  // 8M floats
    size_t partials_bytes = partials_elems * sizeof(float);                   // 32 MB
    size_t counts_elems   = (size_t)NBINS * NBLK2;
    size_t counts_bytes   = counts_elems * sizeof(int);                       // 512 KB
    size_t small_bytes    = (size_t)(NBINS + NBINS + 1 + 16) * sizeof(int);
    size_t need = pairs_bytes + partials_bytes + counts_bytes + small_bytes;

    bool fast = (ws_size >= need) && (n_nodes <= NBINS * BIN_SIZE) && (n_edges >= 4);

    if (fast) {
        uint2* pairs    = (uint2*)d_ws;
        float* partials = (float*)((char*)d_ws + pairs_bytes);
        int*   counts   = (int*)((char*)d_ws + pairs_bytes + partials_bytes);
        int*   bin_tot  = counts + counts_elems;
        int*   bin_base = bin_tot + NBINS;

        hipMemsetAsync(bin_tot, 0, NBINS * sizeof(int), stream);
        hist_kernel<<<NBLK2, BLK2, 0, stream>>>(edge_dst, n_edges, counts, bin_tot);
        scan_bins_kernel<<<1, NBINS, 0, stream>>>(bin_tot, bin_base);
        scan_blocks_kernel<<<NBINS, NBLK2, 0, stream>>>(counts, bin_base);
        scatter_kernel<<<NBLK2, BLK2, 0, stream>>>(node_output, edge_weight,
                                                   edge_src, edge_dst,
                                                   counts, pairs, n_edges);
        accum_kernel<<<NBINS * SSUB, 512, 0, stream>>>(pairs, bin_base, partials);
        int nb = (n_nodes + 511) / 512;
        node_fused_kernel<<<nb, 512, 0, stream>>>(partials, node_params, out, n_nodes);
    } else {
        float* agg = (float*)d_ws;
        int zb = (n_nodes + 255) / 256;
        zero_kernel<<<zb, 256, 0, stream>>>(agg, n_nodes);
        edge_kernel<<<4096, 256, 0, stream>>>(node_output, edge_weight,
                                              edge_src, edge_dst, agg, n_edges);
        node_kernel<<<zb, 256, 0, stream>>>(agg, node_params, out, n_nodes);
    }
}

// Round 5
// 538.745 us; speedup vs baseline: 2.8947x; 1.1144x over previous
//
#include <hip/hip_runtime.h>
#include <math.h>

// ---------------- multisplit parameters ----------------
#define NBINS      128          // bin = dst >> 13 ; covers up to 2^20 nodes
#define BIN_SHIFT  13
#define BIN_SIZE   8192         // nodes per bin (32 KB fp32 in LDS), 13-bit local id
#define NBLK2      2048         // blocks in hist/scatter
#define BLK2       256          // threads in hist/scatter
#define TILE       4096         // edges per tile (16 per thread)
#define SSUB       8            // sub-blocks per bin in accumulate

// clang ext_vector types: accepted by __builtin_nontemporal_load/store
typedef int   vint4   __attribute__((ext_vector_type(4)));
typedef float vfloat4 __attribute__((ext_vector_type(4)));

// pack: fp32 msg rounded to 10 mantissa bits, low 13 bits = dst_local
__device__ __forceinline__ unsigned pack_pair(float m, int dst) {
    unsigned u = __float_as_uint(m);
    u = (u + 0x1000u) & 0xFFFFE000u;          // round-to-nearest at bit 13
    return u | (unsigned)(dst & (BIN_SIZE - 1));
}

// ============================================================
// FAST PATH: deterministic multisplit + tile-local sort + LDS accumulation
// ============================================================

// K1: per-(block,bin) histogram of dst — tile mapping IDENTICAL to scatter
__global__ __launch_bounds__(BLK2) void hist_kernel(
    const int* __restrict__ edge_dst, int n_edges,
    int* __restrict__ counts_g,      // [NBINS][NBLK2]
    int* __restrict__ bin_tot)       // [NBINS], pre-zeroed
{
    __shared__ int cnt[NBINS];
    int tid = threadIdx.x;
    for (int i = tid; i < NBINS; i += BLK2) cnt[i] = 0;
    __syncthreads();

    int ntiles = (n_edges + TILE - 1) / TILE;
    for (int t = blockIdx.x; t < ntiles; t += gridDim.x) {
        int base = t * TILE;
        #pragma unroll
        for (int g = 0; g < 4; ++g) {
            int e = base + g * (TILE / 4) + tid * 4;
            if (e + 3 < n_edges) {
                vint4 d = __builtin_nontemporal_load((const vint4*)(edge_dst + e));
                atomicAdd(&cnt[d.x >> BIN_SHIFT], 1);
                atomicAdd(&cnt[d.y >> BIN_SHIFT], 1);
                atomicAdd(&cnt[d.z >> BIN_SHIFT], 1);
                atomicAdd(&cnt[d.w >> BIN_SHIFT], 1);
            } else {
                for (int k = e; k < n_edges && k < e + 4; ++k)
                    atomicAdd(&cnt[edge_dst[k] >> BIN_SHIFT], 1);
            }
        }
    }
    __syncthreads();
    for (int i = tid; i < NBINS; i += BLK2) {
        counts_g[i * NBLK2 + blockIdx.x] = cnt[i];
        atomicAdd(&bin_tot[i], cnt[i]);          // int atomics: deterministic
    }
}

// K2: exclusive scan of bin totals -> bin_base[NBINS+1]
__global__ __launch_bounds__(NBINS) void scan_bins_kernel(
    const int* __restrict__ bin_tot, int* __restrict__ bin_base)
{
    __shared__ int s[NBINS];
    int tid = threadIdx.x;
    int x = bin_tot[tid];
    s[tid] = x;
    __syncthreads();
    for (int off = 1; off < NBINS; off <<= 1) {
        int t = (tid >= off) ? s[tid - off] : 0;
        __syncthreads();
        s[tid] += t;
        __syncthreads();
    }
    bin_base[tid + 1] = s[tid];                  // inclusive -> base[i+1]
    if (tid == 0) bin_base[0] = 0;
}

// K3: per-bin exclusive scan over NBLK2=2048 block counts (1024 thr, 2 elems each)
__global__ __launch_bounds__(1024) void scan_blocks_kernel(
    int* __restrict__ counts_g, const int* __restrict__ bin_base)
{
    __shared__ int s[1024];
    int b = blockIdx.x, tid = threadIdx.x;
    int v0 = counts_g[b * NBLK2 + 2 * tid];
    int v1 = counts_g[b * NBLK2 + 2 * tid + 1];
    int sum = v0 + v1;
    s[tid] = sum;
    __syncthreads();
    for (int off = 1; off < 1024; off <<= 1) {
        int t = (tid >= off) ? s[tid - off] : 0;
        __syncthreads();
        s[tid] += t;
        __syncthreads();
    }
    int excl = s[tid] - sum + bin_base[b];
    counts_g[b * NBLK2 + 2 * tid]     = excl;
    counts_g[b * NBLK2 + 2 * tid + 1] = excl + v0;
}

// K4: tile-local sort by bin in LDS, then coalesced bulk write of packed pairs
__global__ __launch_bounds__(BLK2) void scatter_kernel(
    const float* __restrict__ node_output,
    const float* __restrict__ edge_weight,
    const int* __restrict__ edge_src,
    const int* __restrict__ edge_dst,
    const int* __restrict__ offsets_g,   // [NBINS][NBLK2]
    unsigned* __restrict__ pairs,
    int n_edges)
{
    __shared__ int gcur[NBINS];          // running global cursor per bin
    __shared__ int gbase[NBINS];         // snapshot for current tile
    __shared__ int hist[NBINS];
    __shared__ int binoff[NBINS + 1];    // per-tile exclusive scan
    __shared__ int cursor[NBINS];        // per-tile placement cursor
    __shared__ unsigned pl[TILE];        // bin-sorted staging (packed)
    __shared__ unsigned char binid[TILE];

    int tid = threadIdx.x, blk = blockIdx.x;
    for (int i = tid; i < NBINS; i += BLK2) {
        gcur[i] = offsets_g[i * NBLK2 + blk];
        hist[i] = 0;
    }
    __syncthreads();

    int ntiles = (n_edges + TILE - 1) / TILE;
    for (int t = blk; t < ntiles; t += gridDim.x) {
        int base = t * TILE;
        int   d[16];
        float m[16];

        // phase A: load + msg + per-tile histogram
        #pragma unroll
        for (int g = 0; g < 4; ++g) {
            int e = base + g * (TILE / 4) + tid * 4;
            if (e + 3 < n_edges) {
                vint4   s4 = __builtin_nontemporal_load((const vint4*)(edge_src + e));
                vint4   d4 = __builtin_nontemporal_load((const vint4*)(edge_dst + e));
                vfloat4 w4 = __builtin_nontemporal_load((const vfloat4*)(edge_weight + e));
                d[4*g+0] = d4.x; m[4*g+0] = node_output[s4.x] * w4.x;
                d[4*g+1] = d4.y; m[4*g+1] = node_output[s4.y] * w4.y;
                d[4*g+2] = d4.z; m[4*g+2] = node_output[s4.z] * w4.z;
                d[4*g+3] = d4.w; m[4*g+3] = node_output[s4.w] * w4.w;
            } else {
                #pragma unroll
                for (int j = 0; j < 4; ++j) {
                    int k = e + j;
                    if (k < n_edges) {
                        d[4*g+j] = edge_dst[k];
                        m[4*g+j] = node_output[edge_src[k]] * edge_weight[k];
                    } else {
                        d[4*g+j] = -1;
                    }
                }
            }
        }
        #pragma unroll
        for (int j = 0; j < 16; ++j)
            if (d[j] >= 0) atomicAdd(&hist[d[j] >> BIN_SHIFT], 1);
        __syncthreads();                                   // sync 1

        // phase B: wave0 scans hist, snapshots/advances gcur, resets hist
        if (tid < 64) {
            int a = hist[2*tid], b2 = hist[2*tid+1];
            int s = a + b2;
            #pragma unroll
            for (int off = 1; off < 64; off <<= 1) {
                int v = __shfl_up(s, off);
                if (tid >= off) s += v;
            }
            int excl = s - (a + b2);
            binoff[2*tid]   = excl;      cursor[2*tid]   = excl;
            binoff[2*tid+1] = excl + a;  cursor[2*tid+1] = excl + a;
            if (tid == 63) binoff[NBINS] = s;
            int g0 = gcur[2*tid], g1 = gcur[2*tid+1];
            gbase[2*tid]   = g0;  gcur[2*tid]   = g0 + a;
            gbase[2*tid+1] = g1;  gcur[2*tid+1] = g1 + b2;
            hist[2*tid] = 0;  hist[2*tid+1] = 0;           // reset for next tile
        }
        __syncthreads();                                   // sync 2
        int tcount = binoff[NBINS];

        // phase C: place packed pairs into bin-sorted LDS staging
        #pragma unroll
        for (int j = 0; j < 16; ++j) {
            if (d[j] >= 0) {
                int b = d[j] >> BIN_SHIFT;
                int pos = atomicAdd(&cursor[b], 1);
                pl[pos] = pack_pair(m[j], d[j]);
                binid[pos] = (unsigned char)b;
            }
        }
        __syncthreads();                                   // sync 3

        // phase D: coalesced write-out (runs of ~32 consecutive addrs per segment)
        for (int k = tid; k < tcount; k += BLK2) {
            int b = binid[k];
            unsigned v = pl[k];
            __builtin_nontemporal_store(v, &pairs[gbase[b] + (k - binoff[b])]);
        }
        __syncthreads();                                   // sync 4 (pl reuse)
    }
}

// K5: per-(bin, sub-block) LDS accumulation -> partials
__global__ __launch_bounds__(512) void accum_kernel(
    const unsigned* __restrict__ pairs,
    const int* __restrict__ bin_base,
    float* __restrict__ partials)        // [NBINS*SSUB][BIN_SIZE]
{
    __shared__ float acc[BIN_SIZE];
    int b = blockIdx.x / SSUB, s = blockIdx.x % SSUB, tid = threadIdx.x;
    for (int i = tid; i < BIN_SIZE; i += blockDim.x) acc[i] = 0.0f;
    __syncthreads();

    int lo = bin_base[b], hi = bin_base[b + 1];
    int tot = hi - lo;
    int chunk = (tot + SSUB - 1) / SSUB;
    int start = lo + s * chunk;
    int end = min(start + chunk, hi);
    for (int i = start + tid; i < end; i += blockDim.x) {
        unsigned v = __builtin_nontemporal_load(&pairs[i]);
        atomicAdd(&acc[v & (BIN_SIZE - 1)],
                  __uint_as_float(v & 0xFFFFE000u));       // LDS fp32 atomic
    }
    __syncthreads();

    float4* dst = (float4*)(partials + (size_t)blockIdx.x * BIN_SIZE);
    const float4* src = (const float4*)acc;
    for (int i = tid; i < BIN_SIZE / 4; i += blockDim.x) dst[i] = src[i];
}

// K6: fused partial-reduce + elementwise math
__global__ __launch_bounds__(512) void node_fused_kernel(
    const float* __restrict__ partials,
    const float* __restrict__ node_params,
    float* __restrict__ out, int n)
{
    int i = blockIdx.x * blockDim.x + threadIdx.x;
    if (i >= n) return;
    int b = i >> BIN_SHIFT, j = i & (BIN_SIZE - 1);
    const float* pb = partials + ((size_t)b * SSUB) * BIN_SIZE + j;
    float x = 0.0f;
    #pragma unroll
    for (int s = 0; s < SSUB; ++s) x += pb[(size_t)s * BIN_SIZE];
    const float* p = node_params + (size_t)i * 7;
    x += p[0];
    out[i] = p[1] * tanhf(x) * sinf(p[2] * x + p[3]) + p[4] * x + p[5];
}

// ============================================================
// FALLBACK PATH (atomic version) if ws too small
// ============================================================
__global__ __launch_bounds__(256) void zero_kernel(float* __restrict__ agg, int n) {
    int i = blockIdx.x * blockDim.x + threadIdx.x;
    if (i < n) agg[i] = 0.0f;
}
__global__ __launch_bounds__(256) void edge_kernel(
    const float* __restrict__ node_output, const float* __restrict__ edge_weight,
    const int* __restrict__ edge_src, const int* __restrict__ edge_dst,
    float* __restrict__ agg, int n_edges)
{
    int tid = blockIdx.x * blockDim.x + threadIdx.x;
    int stride = gridDim.x * blockDim.x;
    int n4 = n_edges >> 2;
    for (int i = tid; i < n4; i += stride) {
        int4   src = ((const int4*)edge_src)[i];
        int4   dst = ((const int4*)edge_dst)[i];
        float4 w   = ((const float4*)edge_weight)[i];
        atomicAdd(&agg[dst.x], node_output[src.x] * w.x);
        atomicAdd(&agg[dst.y], node_output[src.y] * w.y);
        atomicAdd(&agg[dst.z], node_output[src.z] * w.z);
        atomicAdd(&agg[dst.w], node_output[src.w] * w.w);
    }
    for (int i = (n4 << 2) + tid; i < n_edges; i += stride)
        atomicAdd(&agg[edge_dst[i]], node_output[edge_src[i]] * edge_weight[i]);
}
__global__ __launch_bounds__(256) void node_kernel(
    const float* __restrict__ agg, const float* __restrict__ node_params,
    float* __restrict__ out, int n)
{
    int i = blockIdx.x * blockDim.x + threadIdx.x;
    if (i >= n) return;
    const float* p = node_params + (size_t)i * 7;
    float x = agg[i] + p[0];
    out[i] = p[1] * tanhf(x) * sinf(p[2] * x + p[3]) + p[4] * x + p[5];
}

// ============================================================
extern "C" void kernel_launch(void* const* d_in, const int* in_sizes, int n_in,
                              void* d_out, int out_size, void* d_ws, size_t ws_size,
                              hipStream_t stream) {
    const float* node_output = (const float*)d_in[0];
    const float* edge_weight = (const float*)d_in[1];
    const float* node_params = (const float*)d_in[2];
    const int*   edge_src    = (const int*)d_in[3];
    const int*   edge_dst    = (const int*)d_in[4];
    float* out = (float*)d_out;

    int n_nodes = in_sizes[0];
    int n_edges = in_sizes[1];

    // workspace layout
    size_t pairs_bytes    = (size_t)n_edges * sizeof(unsigned);               // 128 MB
    size_t partials_elems = (size_t)NBINS * SSUB * BIN_SIZE;                  // 8M floats
    size_t partials_bytes = partials_elems * sizeof(float);                   // 32 MB
    size_t counts_elems   = (size_t)NBINS * NBLK2;
    size_t counts_bytes   = counts_elems * sizeof(int);                       // 1 MB
    size_t small_bytes    = (size_t)(NBINS + NBINS + 1 + 16) * sizeof(int);
    size_t need = pairs_bytes + partials_bytes + counts_bytes + small_bytes;

    bool fast = (ws_size >= need) && (n_nodes <= NBINS * BIN_SIZE) && (n_edges >= 4);

    if (fast) {
        unsigned* pairs = (unsigned*)d_ws;
        float* partials = (float*)((char*)d_ws + pairs_bytes);
        int*   counts   = (int*)((char*)d_ws + pairs_bytes + partials_bytes);
        int*   bin_tot  = counts + counts_elems;
        int*   bin_base = bin_tot + NBINS;

        (void)hipMemsetAsync(bin_tot, 0, NBINS * sizeof(int), stream);
        hist_kernel<<<NBLK2, BLK2, 0, stream>>>(edge_dst, n_edges, counts, bin_tot);
        scan_bins_kernel<<<1, NBINS, 0, stream>>>(bin_tot, bin_base);
        scan_blocks_kernel<<<NBINS, 1024, 0, stream>>>(counts, bin_base);
        scatter_kernel<<<NBLK2, BLK2, 0, stream>>>(node_output, edge_weight,
                                                   edge_src, edge_dst,
                                                   counts, pairs, n_edges);
        accum_kernel<<<NBINS * SSUB, 512, 0, stream>>>(pairs, bin_base, partials);
        int nb = (n_nodes + 511) / 512;
        node_fused_kernel<<<nb, 512, 0, stream>>>(partials, node_params, out, n_nodes);
    } else {
        float* agg = (float*)d_ws;
        int zb = (n_nodes + 255) / 256;
        zero_kernel<<<zb, 256, 0, stream>>>(agg, n_nodes);
        edge_kernel<<<4096, 256, 0, stream>>>(node_output, edge_weight,
                                              edge_src, edge_dst, agg, n_edges);
        node_kernel<<<zb, 256, 0, stream>>>(agg, node_params, out, n_nodes);
    }
}

// Round 6
// 442.437 us; speedup vs baseline: 3.5248x; 1.2177x over previous
//
#include <hip/hip_runtime.h>
#include <math.h>

// ---------------- multisplit parameters ----------------
#define NBINS      128          // bin = dst >> 13
#define BIN_SHIFT  13
#define BIN_SIZE   8192         // nodes per bin (32 KB fp32 in LDS), 13-bit local id
#define NBLK2      1024         // blocks in scatter
#define BLK2       512          // threads in scatter
#define TILE       8192         // edges per tile (16 per thread)
#define SSUB       8            // sub-blocks per bin in accumulate

typedef int      vint4   __attribute__((ext_vector_type(4)));
typedef float    vfloat4 __attribute__((ext_vector_type(4)));
typedef unsigned vuint4  __attribute__((ext_vector_type(4)));

// pack: fp32 msg rounded to 10 mantissa bits, low 13 bits = dst_local
__device__ __forceinline__ unsigned pack_pair(float m, int dst) {
    unsigned u = __float_as_uint(m);
    u = (u + 0x1000u) & 0xFFFFE000u;          // round-to-nearest at bit 13
    return u | (unsigned)(dst & (BIN_SIZE - 1));
}

// ============================================================
// FAST PATH: tile-positional multisplit (no global prefix pass)
// ============================================================

// K1: per-tile bin-sort in LDS; write pairs tile-positionally + binoff16 table
__global__ __launch_bounds__(BLK2) void scatter_kernel(
    const float* __restrict__ node_output,
    const float* __restrict__ edge_weight,
    const int* __restrict__ edge_src,
    const int* __restrict__ edge_dst,
    unsigned* __restrict__ pairs,          // [ntiles*TILE] tile-positional
    unsigned short* __restrict__ binoff16, // [ntiles][NBINS] per-tile excl scan
    int n_edges)
{
    __shared__ int hist[NBINS];
    __shared__ int binoff[NBINS + 1];
    __shared__ int cursor[NBINS];
    __shared__ __align__(16) unsigned pl[TILE];   // bin-sorted staging

    int tid = threadIdx.x, blk = blockIdx.x;
    for (int i = tid; i < NBINS; i += BLK2) hist[i] = 0;
    __syncthreads();

    int ntiles = (n_edges + TILE - 1) / TILE;
    for (int t = blk; t < ntiles; t += gridDim.x) {
        int tbase = t * TILE;
        int   d[16];
        float m[16];

        // phase A: load + msg + per-tile histogram
        #pragma unroll
        for (int g = 0; g < 4; ++g) {
            int e = tbase + g * (TILE / 4) + tid * 4;
            if (e + 3 < n_edges) {
                vint4   s4 = __builtin_nontemporal_load((const vint4*)(edge_src + e));
                vint4   d4 = __builtin_nontemporal_load((const vint4*)(edge_dst + e));
                vfloat4 w4 = __builtin_nontemporal_load((const vfloat4*)(edge_weight + e));
                d[4*g+0] = d4.x; m[4*g+0] = node_output[s4.x] * w4.x;
                d[4*g+1] = d4.y; m[4*g+1] = node_output[s4.y] * w4.y;
                d[4*g+2] = d4.z; m[4*g+2] = node_output[s4.z] * w4.z;
                d[4*g+3] = d4.w; m[4*g+3] = node_output[s4.w] * w4.w;
            } else {
                #pragma unroll
                for (int j = 0; j < 4; ++j) {
                    int k = e + j;
                    if (k < n_edges) {
                        d[4*g+j] = edge_dst[k];
                        m[4*g+j] = node_output[edge_src[k]] * edge_weight[k];
                    } else {
                        d[4*g+j] = -1;
                    }
                }
            }
        }
        #pragma unroll
        for (int j = 0; j < 16; ++j)
            if (d[j] >= 0) atomicAdd(&hist[d[j] >> BIN_SHIFT], 1);
        __syncthreads();                                   // sync 1

        // phase B: wave0 scans hist -> binoff/cursor, writes binoff16, resets hist
        if (tid < 64) {
            int a = hist[2*tid], b2 = hist[2*tid+1];
            int s = a + b2;
            #pragma unroll
            for (int off = 1; off < 64; off <<= 1) {
                int v = __shfl_up(s, off);
                if (tid >= off) s += v;
            }
            int excl = s - (a + b2);
            binoff[2*tid]   = excl;      cursor[2*tid]   = excl;
            binoff[2*tid+1] = excl + a;  cursor[2*tid+1] = excl + a;
            if (tid == 63) binoff[NBINS] = s;
            // coalesced 256B store of the exclusive scan (2 ushorts per lane)
            ((unsigned*)(binoff16 + (size_t)t * NBINS))[tid] =
                (unsigned)(excl & 0xFFFF) | ((unsigned)((excl + a) & 0xFFFF) << 16);
            hist[2*tid] = 0;  hist[2*tid+1] = 0;           // reset for next tile
        }
        __syncthreads();                                   // sync 2
        int tcount = binoff[NBINS];

        // phase C: place packed pairs into bin-sorted LDS staging
        #pragma unroll
        for (int j = 0; j < 16; ++j) {
            if (d[j] >= 0) {
                int b = d[j] >> BIN_SHIFT;
                int pos = atomicAdd(&cursor[b], 1);
                pl[pos] = pack_pair(m[j], d[j]);
            }
        }
        __syncthreads();                                   // sync 3

        // phase D: pure contiguous copy LDS -> global (vector dwordx4)
        int nv = tcount >> 2;
        for (int k = tid; k < nv; k += BLK2) {
            vuint4 v = *(const vuint4*)&pl[4 * k];
            __builtin_nontemporal_store(v, (vuint4*)(pairs + tbase + 4 * k));
        }
        for (int k = (nv << 2) + tid; k < tcount; k += BLK2)
            pairs[tbase + k] = pl[k];
        __syncthreads();                                   // sync 4 (pl reuse)
    }
}

// K2: per-(bin, sub) accumulation; wave-per-tile-segment via binoff16
__global__ __launch_bounds__(512) void accum_kernel(
    const unsigned* __restrict__ pairs,
    const unsigned short* __restrict__ binoff16,
    float* __restrict__ partials,        // [NBINS*SSUB][BIN_SIZE]
    int n_edges)
{
    __shared__ float acc[BIN_SIZE];
    int b = blockIdx.x / SSUB, s = blockIdx.x % SSUB, tid = threadIdx.x;
    for (int i = tid; i < BIN_SIZE; i += blockDim.x) acc[i] = 0.0f;
    __syncthreads();

    int ntiles = (n_edges + TILE - 1) / TILE;
    int wave = tid >> 6, lane = tid & 63;

    // block (b,s) owns tiles t % SSUB == s; its 8 waves stride those by 8
    for (int t = s + SSUB * wave; t < ntiles; t += SSUB * 8) {
        const unsigned short* row = binoff16 + (size_t)t * NBINS;
        int off = row[b];
        int end = (b < NBINS - 1) ? (int)row[b + 1]
                                  : min(TILE, n_edges - t * TILE);
        int tb = t * TILE;
        for (int k = off + lane; k < end; k += 64) {
            unsigned v = __builtin_nontemporal_load(&pairs[tb + k]);
            atomicAdd(&acc[v & (BIN_SIZE - 1)],
                      __uint_as_float(v & 0xFFFFE000u));
        }
    }
    __syncthreads();

    float4* dst = (float4*)(partials + (size_t)blockIdx.x * BIN_SIZE);
    const float4* src = (const float4*)acc;
    for (int i = tid; i < BIN_SIZE / 4; i += blockDim.x) dst[i] = src[i];
}

// K3: fused partial-reduce + elementwise math
__global__ __launch_bounds__(512) void node_fused_kernel(
    const float* __restrict__ partials,
    const float* __restrict__ node_params,
    float* __restrict__ out, int n)
{
    int i = blockIdx.x * blockDim.x + threadIdx.x;
    if (i >= n) return;
    int b = i >> BIN_SHIFT, j = i & (BIN_SIZE - 1);
    const float* pb = partials + ((size_t)b * SSUB) * BIN_SIZE + j;
    float x = 0.0f;
    #pragma unroll
    for (int s = 0; s < SSUB; ++s) x += pb[(size_t)s * BIN_SIZE];
    const float* p = node_params + (size_t)i * 7;
    x += p[0];
    out[i] = p[1] * tanhf(x) * sinf(p[2] * x + p[3]) + p[4] * x + p[5];
}

// ============================================================
// FALLBACK PATH (atomic version) if ws too small
// ============================================================
__global__ __launch_bounds__(256) void zero_kernel(float* __restrict__ agg, int n) {
    int i = blockIdx.x * blockDim.x + threadIdx.x;
    if (i < n) agg[i] = 0.0f;
}
__global__ __launch_bounds__(256) void edge_kernel(
    const float* __restrict__ node_output, const float* __restrict__ edge_weight,
    const int* __restrict__ edge_src, const int* __restrict__ edge_dst,
    float* __restrict__ agg, int n_edges)
{
    int tid = blockIdx.x * blockDim.x + threadIdx.x;
    int stride = gridDim.x * blockDim.x;
    int n4 = n_edges >> 2;
    for (int i = tid; i < n4; i += stride) {
        int4   src = ((const int4*)edge_src)[i];
        int4   dst = ((const int4*)edge_dst)[i];
        float4 w   = ((const float4*)edge_weight)[i];
        atomicAdd(&agg[dst.x], node_output[src.x] * w.x);
        atomicAdd(&agg[dst.y], node_output[src.y] * w.y);
        atomicAdd(&agg[dst.z], node_output[src.z] * w.z);
        atomicAdd(&agg[dst.w], node_output[src.w] * w.w);
    }
    for (int i = (n4 << 2) + tid; i < n_edges; i += stride)
        atomicAdd(&agg[edge_dst[i]], node_output[edge_src[i]] * edge_weight[i]);
}
__global__ __launch_bounds__(256) void node_kernel(
    const float* __restrict__ agg, const float* __restrict__ node_params,
    float* __restrict__ out, int n)
{
    int i = blockIdx.x * blockDim.x + threadIdx.x;
    if (i >= n) return;
    const float* p = node_params + (size_t)i * 7;
    float x = agg[i] + p[0];
    out[i] = p[1] * tanhf(x) * sinf(p[2] * x + p[3]) + p[4] * x + p[5];
}

// ============================================================
extern "C" void kernel_launch(void* const* d_in, const int* in_sizes, int n_in,
                              void* d_out, int out_size, void* d_ws, size_t ws_size,
                              hipStream_t stream) {
    const float* node_output = (const float*)d_in[0];
    const float* edge_weight = (const float*)d_in[1];
    const float* node_params = (const float*)d_in[2];
    const int*   edge_src    = (const int*)d_in[3];
    const int*   edge_dst    = (const int*)d_in[4];
    float* out = (float*)d_out;

    int n_nodes = in_sizes[0];
    int n_edges = in_sizes[1];
    int ntiles  = (n_edges + TILE - 1) / TILE;

    // workspace layout
    size_t pairs_bytes    = (size_t)ntiles * TILE * sizeof(unsigned);         // 128 MB
    size_t partials_elems = (size_t)NBINS * SSUB * BIN_SIZE;                  // 8M floats
    size_t partials_bytes = partials_elems * sizeof(float);                   // 32 MB
    size_t binoff_bytes   = (size_t)ntiles * NBINS * sizeof(unsigned short);  // ~1 MB
    size_t need = pairs_bytes + partials_bytes + binoff_bytes + 256;

    bool fast = (ws_size >= need) && (n_nodes <= NBINS * BIN_SIZE) && (n_edges >= 4);

    if (fast) {
        unsigned* pairs = (unsigned*)d_ws;
        float* partials = (float*)((char*)d_ws + pairs_bytes);
        unsigned short* binoff16 =
            (unsigned short*)((char*)d_ws + pairs_bytes + partials_bytes);

        scatter_kernel<<<NBLK2, BLK2, 0, stream>>>(node_output, edge_weight,
                                                   edge_src, edge_dst,
                                                   pairs, binoff16, n_edges);
        accum_kernel<<<NBINS * SSUB, 512, 0, stream>>>(pairs, binoff16,
                                                       partials, n_edges);
        int nb = (n_nodes + 511) / 512;
        node_fused_kernel<<<nb, 512, 0, stream>>>(partials, node_params, out, n_nodes);
    } else {
        float* agg = (float*)d_ws;
        int zb = (n_nodes + 255) / 256;
        zero_kernel<<<zb, 256, 0, stream>>>(agg, n_nodes);
        edge_kernel<<<4096, 256, 0, stream>>>(node_output, edge_weight,
                                              edge_src, edge_dst, agg, n_edges);
        node_kernel<<<zb, 256, 0, stream>>>(agg, node_params, out, n_nodes);
    }
}

// Round 7
// 436.537 us; speedup vs baseline: 3.5725x; 1.0135x over previous
//
#include <hip/hip_runtime.h>
#include <math.h>

// ---------------- multisplit parameters ----------------
#define NBINS      128          // bin = dst >> 13
#define BIN_SHIFT  13
#define BIN_SIZE   8192         // nodes per bin (32 KB fp32 in LDS), 13-bit local id
#define NBLK2      2048         // blocks in scatter (8 per CU)
#define BLK2       256          // threads in scatter
#define TILE       4096         // edges per tile (16 per thread)
#define SSUB       8            // sub-blocks per bin in accumulate

typedef int      vint4   __attribute__((ext_vector_type(4)));
typedef float    vfloat4 __attribute__((ext_vector_type(4)));
typedef unsigned vuint4  __attribute__((ext_vector_type(4)));

// pack: fp32 msg rounded to 10 mantissa bits, low 13 bits = dst_local
__device__ __forceinline__ unsigned pack_pair(float m, int dst) {
    unsigned u = __float_as_uint(m);
    u = (u + 0x1000u) & 0xFFFFE000u;          // round-to-nearest at bit 13
    return u | (unsigned)(dst & (BIN_SIZE - 1));
}

// ============================================================
// FAST PATH: tile-positional multisplit (no global prefix pass)
// ============================================================

// K1: per-tile bin-sort in LDS; write pairs tile-positionally + binoff16 table
__global__ __launch_bounds__(BLK2) void scatter_kernel(
    const float* __restrict__ node_output,
    const float* __restrict__ edge_weight,
    const int* __restrict__ edge_src,
    const int* __restrict__ edge_dst,
    unsigned* __restrict__ pairs,          // [ntiles*TILE] tile-positional
    unsigned short* __restrict__ binoff16, // [ntiles][NBINS] per-tile excl scan
    int n_edges)
{
    __shared__ int hist[NBINS];
    __shared__ int binoff[NBINS + 1];
    __shared__ int cursor[NBINS];
    __shared__ __align__(16) unsigned pl[TILE];   // bin-sorted staging

    int tid = threadIdx.x, blk = blockIdx.x;
    for (int i = tid; i < NBINS; i += BLK2) hist[i] = 0;
    __syncthreads();

    int ntiles = (n_edges + TILE - 1) / TILE;
    for (int t = blk; t < ntiles; t += gridDim.x) {
        int tbase = t * TILE;
        int      d[16];
        unsigned pk[16];

        if (tbase + TILE <= n_edges) {
            // -------- fast path: whole tile in range, straight-line loads
            vint4 s4[4]; vint4 d4[4]; vfloat4 w4[4];
            #pragma unroll
            for (int g = 0; g < 4; ++g) {
                int e = tbase + g * (TILE / 4) + tid * 4;
                s4[g] = __builtin_nontemporal_load((const vint4*)(edge_src + e));
                d4[g] = __builtin_nontemporal_load((const vint4*)(edge_dst + e));
                w4[g] = __builtin_nontemporal_load((const vfloat4*)(edge_weight + e));
            }
            // hist first — depends only on d4
            #pragma unroll
            for (int g = 0; g < 4; ++g) {
                d[4*g+0] = d4[g].x; d[4*g+1] = d4[g].y;
                d[4*g+2] = d4[g].z; d[4*g+3] = d4[g].w;
            }
            #pragma unroll
            for (int j = 0; j < 16; ++j)
                atomicAdd(&hist[d[j] >> BIN_SHIFT], 1);
            // 16 independent gathers
            float no[16];
            #pragma unroll
            for (int g = 0; g < 4; ++g) {
                no[4*g+0] = node_output[s4[g].x];
                no[4*g+1] = node_output[s4[g].y];
                no[4*g+2] = node_output[s4[g].z];
                no[4*g+3] = node_output[s4[g].w];
            }
            #pragma unroll
            for (int g = 0; g < 4; ++g) {
                pk[4*g+0] = pack_pair(no[4*g+0] * w4[g].x, d[4*g+0]);
                pk[4*g+1] = pack_pair(no[4*g+1] * w4[g].y, d[4*g+1]);
                pk[4*g+2] = pack_pair(no[4*g+2] * w4[g].z, d[4*g+2]);
                pk[4*g+3] = pack_pair(no[4*g+3] * w4[g].w, d[4*g+3]);
            }
        } else {
            // -------- tail tile: guarded scalar path
            #pragma unroll
            for (int g = 0; g < 4; ++g) {
                #pragma unroll
                for (int j = 0; j < 4; ++j) {
                    int k = tbase + g * (TILE / 4) + tid * 4 + j;
                    if (k < n_edges) {
                        d[4*g+j]  = edge_dst[k];
                        pk[4*g+j] = pack_pair(node_output[edge_src[k]] * edge_weight[k],
                                              d[4*g+j]);
                    } else {
                        d[4*g+j] = -1;
                    }
                }
            }
            #pragma unroll
            for (int j = 0; j < 16; ++j)
                if (d[j] >= 0) atomicAdd(&hist[d[j] >> BIN_SHIFT], 1);
        }
        __syncthreads();                                   // sync 1

        // phase B: wave0 scans hist -> binoff/cursor, writes binoff16, resets hist
        if (tid < 64) {
            int a = hist[2*tid], b2 = hist[2*tid+1];
            int s = a + b2;
            #pragma unroll
            for (int off = 1; off < 64; off <<= 1) {
                int v = __shfl_up(s, off);
                if (tid >= off) s += v;
            }
            int excl = s - (a + b2);
            binoff[2*tid]   = excl;      cursor[2*tid]   = excl;
            binoff[2*tid+1] = excl + a;  cursor[2*tid+1] = excl + a;
            if (tid == 63) binoff[NBINS] = s;
            // coalesced 256B store of the exclusive scan (2 ushorts per lane)
            ((unsigned*)(binoff16 + (size_t)t * NBINS))[tid] =
                (unsigned)(excl & 0xFFFF) | ((unsigned)((excl + a) & 0xFFFF) << 16);
            hist[2*tid] = 0;  hist[2*tid+1] = 0;           // reset for next tile
        }
        __syncthreads();                                   // sync 2
        int tcount = binoff[NBINS];

        // phase C: place packed pairs into bin-sorted LDS staging
        if (tcount == TILE) {
            #pragma unroll
            for (int j = 0; j < 16; ++j) {
                int pos = atomicAdd(&cursor[d[j] >> BIN_SHIFT], 1);
                pl[pos] = pk[j];
            }
        } else {
            #pragma unroll
            for (int j = 0; j < 16; ++j) {
                if (d[j] >= 0) {
                    int pos = atomicAdd(&cursor[d[j] >> BIN_SHIFT], 1);
                    pl[pos] = pk[j];
                }
            }
        }
        __syncthreads();                                   // sync 3

        // phase D: pure contiguous copy LDS -> global (vector dwordx4)
        int nv = tcount >> 2;
        for (int k = tid; k < nv; k += BLK2) {
            vuint4 v = *(const vuint4*)&pl[4 * k];
            __builtin_nontemporal_store(v, (vuint4*)(pairs + tbase + 4 * k));
        }
        for (int k = (nv << 2) + tid; k < tcount; k += BLK2)
            pairs[tbase + k] = pl[k];
        __syncthreads();                                   // sync 4 (pl reuse)
    }
}

// K2: per-(bin, sub) accumulation; wave-per-tile-segment via binoff16
__global__ __launch_bounds__(512) void accum_kernel(
    const unsigned* __restrict__ pairs,
    const unsigned short* __restrict__ binoff16,
    float* __restrict__ partials,        // [NBINS*SSUB][BIN_SIZE]
    int n_edges)
{
    __shared__ float acc[BIN_SIZE];
    int b = blockIdx.x / SSUB, s = blockIdx.x % SSUB, tid = threadIdx.x;
    for (int i = tid; i < BIN_SIZE; i += blockDim.x) acc[i] = 0.0f;
    __syncthreads();

    int ntiles = (n_edges + TILE - 1) / TILE;
    int wave = tid >> 6, lane = tid & 63;

    // block (b,s) owns tiles t % SSUB == s; its 8 waves stride those by 8
    for (int t = s + SSUB * wave; t < ntiles; t += SSUB * 8) {
        const unsigned short* row = binoff16 + (size_t)t * NBINS;
        int off = row[b];
        int end = (b < NBINS - 1) ? (int)row[b + 1]
                                  : min(TILE, n_edges - t * TILE);
        int tb = t * TILE;
        for (int k = off + lane; k < end; k += 64) {
            unsigned v = __builtin_nontemporal_load(&pairs[tb + k]);
            atomicAdd(&acc[v & (BIN_SIZE - 1)],
                      __uint_as_float(v & 0xFFFFE000u));
        }
    }
    __syncthreads();

    float4* dst = (float4*)(partials + (size_t)blockIdx.x * BIN_SIZE);
    const float4* src = (const float4*)acc;
    for (int i = tid; i < BIN_SIZE / 4; i += blockDim.x) dst[i] = src[i];
}

// K3: fused partial-reduce + elementwise math
__global__ __launch_bounds__(512) void node_fused_kernel(
    const float* __restrict__ partials,
    const float* __restrict__ node_params,
    float* __restrict__ out, int n)
{
    int i = blockIdx.x * blockDim.x + threadIdx.x;
    if (i >= n) return;
    int b = i >> BIN_SHIFT, j = i & (BIN_SIZE - 1);
    const float* pb = partials + ((size_t)b * SSUB) * BIN_SIZE + j;
    float x = 0.0f;
    #pragma unroll
    for (int s = 0; s < SSUB; ++s) x += pb[(size_t)s * BIN_SIZE];
    const float* p = node_params + (size_t)i * 7;
    x += p[0];
    out[i] = p[1] * tanhf(x) * sinf(p[2] * x + p[3]) + p[4] * x + p[5];
}

// ============================================================
// FALLBACK PATH (atomic version) if ws too small
// ============================================================
__global__ __launch_bounds__(256) void zero_kernel(float* __restrict__ agg, int n) {
    int i = blockIdx.x * blockDim.x + threadIdx.x;
    if (i < n) agg[i] = 0.0f;
}
__global__ __launch_bounds__(256) void edge_kernel(
    const float* __restrict__ node_output, const float* __restrict__ edge_weight,
    const int* __restrict__ edge_src, const int* __restrict__ edge_dst,
    float* __restrict__ agg, int n_edges)
{
    int tid = blockIdx.x * blockDim.x + threadIdx.x;
    int stride = gridDim.x * blockDim.x;
    int n4 = n_edges >> 2;
    for (int i = tid; i < n4; i += stride) {
        int4   src = ((const int4*)edge_src)[i];
        int4   dst = ((const int4*)edge_dst)[i];
        float4 w   = ((const float4*)edge_weight)[i];
        atomicAdd(&agg[dst.x], node_output[src.x] * w.x);
        atomicAdd(&agg[dst.y], node_output[src.y] * w.y);
        atomicAdd(&agg[dst.z], node_output[src.z] * w.z);
        atomicAdd(&agg[dst.w], node_output[src.w] * w.w);
    }
    for (int i = (n4 << 2) + tid; i < n_edges; i += stride)
        atomicAdd(&agg[edge_dst[i]], node_output[edge_src[i]] * edge_weight[i]);
}
__global__ __launch_bounds__(256) void node_kernel(
    const float* __restrict__ agg, const float* __restrict__ node_params,
    float* __restrict__ out, int n)
{
    int i = blockIdx.x * blockDim.x + threadIdx.x;
    if (i >= n) return;
    const float* p = node_params + (size_t)i * 7;
    float x = agg[i] + p[0];
    out[i] = p[1] * tanhf(x) * sinf(p[2] * x + p[3]) + p[4] * x + p[5];
}

// ============================================================
extern "C" void kernel_launch(void* const* d_in, const int* in_sizes, int n_in,
                              void* d_out, int out_size, void* d_ws, size_t ws_size,
                              hipStream_t stream) {
    const float* node_output = (const float*)d_in[0];
    const float* edge_weight = (const float*)d_in[1];
    const float* node_params = (const float*)d_in[2];
    const int*   edge_src    = (const int*)d_in[3];
    const int*   edge_dst    = (const int*)d_in[4];
    float* out = (float*)d_out;

    int n_nodes = in_sizes[0];
    int n_edges = in_sizes[1];
    int ntiles  = (n_edges + TILE - 1) / TILE;

    // workspace layout
    size_t pairs_bytes    = (size_t)ntiles * TILE * sizeof(unsigned);         // 128 MB
    size_t partials_elems = (size_t)NBINS * SSUB * BIN_SIZE;                  // 8M floats
    size_t partials_bytes = partials_elems * sizeof(float);                   // 32 MB
    size_t binoff_bytes   = (size_t)ntiles * NBINS * sizeof(unsigned short);  // ~2 MB
    size_t need = pairs_bytes + partials_bytes + binoff_bytes + 256;

    bool fast = (ws_size >= need) && (n_nodes <= NBINS * BIN_SIZE) && (n_edges >= 4);

    if (fast) {
        unsigned* pairs = (unsigned*)d_ws;
        float* partials = (float*)((char*)d_ws + pairs_bytes);
        unsigned short* binoff16 =
            (unsigned short*)((char*)d_ws + pairs_bytes + partials_bytes);

        scatter_kernel<<<NBLK2, BLK2, 0, stream>>>(node_output, edge_weight,
                                                   edge_src, edge_dst,
                                                   pairs, binoff16, n_edges);
        accum_kernel<<<NBINS * SSUB, 512, 0, stream>>>(pairs, binoff16,
                                                       partials, n_edges);
        int nb = (n_nodes + 511) / 512;
        node_fused_kernel<<<nb, 512, 0, stream>>>(partials, node_params, out, n_nodes);
    } else {
        float* agg = (float*)d_ws;
        int zb = (n_nodes + 255) / 256;
        zero_kernel<<<zb, 256, 0, stream>>>(agg, n_nodes);
        edge_kernel<<<4096, 256, 0, stream>>>(node_output, edge_weight,
                                              edge_src, edge_dst, agg, n_edges);
        node_kernel<<<zb, 256, 0, stream>>>(agg, node_params, out, n_nodes);
    }
}